// Round 2
// baseline (964.841 us; speedup 1.0000x reference)
//
#include <hip/hip_runtime.h>

// Problem constants (fixed by the reference): N=32768 tokens, D=2048, P=2 paths.
#define NTOK 32768
#define DDIM 2048

// ---------------------------------------------------------------------------
// Pass 1: per-token gate dot products in fp64 -> mask byte (bit0=path0, bit1=path1)
// One wave (64 lanes) per token; block = 256 threads = 4 tokens.
// x reads fully coalesced (1 KiB per wave instruction via float4).
// ---------------------------------------------------------------------------
__global__ __launch_bounds__(256) void gate_kernel(const float* __restrict__ x,
                                                   const float* __restrict__ W,
                                                   const float* __restrict__ b,
                                                   unsigned char* __restrict__ mask) {
    const int token = blockIdx.x * 4 + (threadIdx.x >> 6);
    const int lane  = threadIdx.x & 63;
    const float4* xr = reinterpret_cast<const float4*>(x + (size_t)token * DDIM);
    const float4* Wv = reinterpret_cast<const float4*>(W);  // W is [D][2] row-major

    double a0 = 0.0, a1 = 0.0;
#pragma unroll
    for (int k = 0; k < DDIM / 4 / 64; ++k) {   // 8 iterations
        const int d4  = k * 64 + lane;          // float4 index into the row
        const float4 xv  = xr[d4];
        const float4 w01 = Wv[2 * d4];          // rows 4*d4, 4*d4+1 of W
        const float4 w23 = Wv[2 * d4 + 1];      // rows 4*d4+2, 4*d4+3
        a0 += (double)xv.x * w01.x + (double)xv.y * w01.z
            + (double)xv.z * w23.x + (double)xv.w * w23.z;
        a1 += (double)xv.x * w01.y + (double)xv.y * w01.w
            + (double)xv.z * w23.y + (double)xv.w * w23.w;
    }
#pragma unroll
    for (int off = 32; off >= 1; off >>= 1) {
        a0 += __shfl_down(a0, off, 64);
        a1 += __shfl_down(a1, off, 64);
    }
    if (lane == 0) {
        const double z0 = a0 + (double)b[0];
        const double z1 = a1 + (double)b[1];
        // sigmoid(z) >= 0.5  <=>  z >= 0
        mask[token] = (unsigned char)((z0 >= 0.0 ? 1u : 0u) | (z1 >= 0.0 ? 2u : 0u));
    }
}

// ---------------------------------------------------------------------------
// Pass 2: single-block exclusive scan over all 32768 mask bytes (both paths
// packed into one u32: low 16 bits = path0 count, high 16 = path1 count;
// totals <= 32768 so fields never overflow into each other).
// 1024 threads x 32 tokens each.
// ---------------------------------------------------------------------------
__global__ __launch_bounds__(1024) void scan_kernel(const unsigned char* __restrict__ mask,
                                                    int* __restrict__ rank0,
                                                    int* __restrict__ rank1,
                                                    int* __restrict__ counts) {
    const int t    = threadIdx.x;
    const int base = t * 32;

    unsigned char m[32];
    unsigned c0 = 0, c1 = 0;
#pragma unroll
    for (int k = 0; k < 32; ++k) {
        m[k] = mask[base + k];
        c0 += (m[k] & 1u);
        c1 += ((m[k] >> 1) & 1u);
    }
    const unsigned packed = c0 | (c1 << 16);

    // wave-level inclusive scan (64 lanes)
    const int lane = t & 63;
    const int wave = t >> 6;
    unsigned inc = packed;
#pragma unroll
    for (int d = 1; d < 64; d <<= 1) {
        const unsigned o = __shfl_up(inc, d, 64);
        if (lane >= d) inc += o;
    }

    __shared__ unsigned wtot[16];
    if (lane == 63) wtot[wave] = inc;
    __syncthreads();
    if (wave == 0) {
        unsigned v = (lane < 16) ? wtot[lane] : 0u;
#pragma unroll
        for (int d = 1; d < 16; d <<= 1) {
            const unsigned o = __shfl_up(v, d, 64);
            if (lane >= d) v += o;
        }
        if (lane < 16) wtot[lane] = v;   // now inclusive wave totals
    }
    __syncthreads();

    const unsigned waveoff = (wave > 0) ? wtot[wave - 1] : 0u;
    const unsigned exc = inc - packed + waveoff;   // exclusive prefix for this thread
    unsigned o0 = exc & 0xffffu;
    unsigned o1 = exc >> 16;
#pragma unroll
    for (int k = 0; k < 32; ++k) {
        rank0[base + k] = (int)o0;
        rank1[base + k] = (int)o1;
        o0 += (m[k] & 1u);
        o1 += ((m[k] >> 1) & 1u);
    }
    if (t == 1023) {
        counts[0] = (int)o0;   // total routed to path 0
        counts[1] = (int)o1;   // total routed to path 1
    }
}

// ---------------------------------------------------------------------------
// Pass 3 (fused): one block per token i.
//   combined[i] = (m0+m1) * x[i]               (always written: data or zeros)
//   if m0: x0[rank0[i]] = x[i];   if i >= count0: x0[i] = 0   (covers all rows)
//   same for path 1. Row coverage is complete and disjoint.
// Block = 256 threads, 2 x float4 per thread = 2048 floats/row.
// ---------------------------------------------------------------------------
__global__ __launch_bounds__(256) void scatter_kernel(const float* __restrict__ x,
                                                      const unsigned char* __restrict__ mask,
                                                      const int* __restrict__ rank0,
                                                      const int* __restrict__ rank1,
                                                      const int* __restrict__ counts,
                                                      float* __restrict__ out) {
    const int i = blockIdx.x;
    const int t = threadIdx.x;
    const unsigned s = mask[i];
    const int c0 = counts[0];
    const int c1 = counts[1];

    float* __restrict__ x0 = out;
    float* __restrict__ x1 = out + (size_t)NTOK * DDIM;
    float* __restrict__ cb = out + (size_t)2 * NTOK * DDIM;

    const float4 z4 = make_float4(0.f, 0.f, 0.f, 0.f);
    float4 v0 = z4, v1 = z4;
    if (s != 0u) {
        const float4* xr = reinterpret_cast<const float4*>(x + (size_t)i * DDIM);
        v0 = xr[t];
        v1 = xr[t + 256];
    }

    // combined
    {
        const float sc = (float)((s & 1u) + ((s >> 1) & 1u));
        float4* d = reinterpret_cast<float4*>(cb + (size_t)i * DDIM);
        d[t]       = make_float4(v0.x * sc, v0.y * sc, v0.z * sc, v0.w * sc);
        d[t + 256] = make_float4(v1.x * sc, v1.y * sc, v1.z * sc, v1.w * sc);
    }
    // path 0
    if (s & 1u) {
        float4* d = reinterpret_cast<float4*>(x0 + (size_t)rank0[i] * DDIM);
        d[t] = v0; d[t + 256] = v1;
    }
    if (i >= c0) {
        float4* d = reinterpret_cast<float4*>(x0 + (size_t)i * DDIM);
        d[t] = z4; d[t + 256] = z4;
    }
    // path 1
    if (s & 2u) {
        float4* d = reinterpret_cast<float4*>(x1 + (size_t)rank1[i] * DDIM);
        d[t] = v0; d[t + 256] = v1;
    }
    if (i >= c1) {
        float4* d = reinterpret_cast<float4*>(x1 + (size_t)i * DDIM);
        d[t] = z4; d[t + 256] = z4;
    }
}

// ---------------------------------------------------------------------------
extern "C" void kernel_launch(void* const* d_in, const int* in_sizes, int n_in,
                              void* d_out, int out_size, void* d_ws, size_t ws_size,
                              hipStream_t stream) {
    const float* x = (const float*)d_in[0];
    const float* W = (const float*)d_in[1];
    const float* b = (const float*)d_in[2];
    float* out = (float*)d_out;

    // workspace layout (all offsets 256B-aligned):
    //   mask:   NTOK bytes
    //   rank0:  NTOK ints
    //   rank1:  NTOK ints
    //   counts: 2 ints
    unsigned char* ws = (unsigned char*)d_ws;
    unsigned char* mask = ws;
    int* rank0  = (int*)(ws + 32768);
    int* rank1  = (int*)(ws + 32768 + 4 * NTOK);
    int* counts = (int*)(ws + 32768 + 8 * NTOK);

    gate_kernel<<<NTOK / 4, 256, 0, stream>>>(x, W, b, mask);
    scan_kernel<<<1, 1024, 0, stream>>>(mask, rank0, rank1, counts);
    scatter_kernel<<<NTOK, 256, 0, stream>>>(x, mask, rank0, rank1, counts, out);
}